// Round 13
// baseline (436.097 us; speedup 1.0000x reference)
//
#include <hip/hip_runtime.h>

// R-GCN (3 layers) on MI355X — Round 13.
// Round-12 lesson: L1's A (115MB) must be read ONCE -> full 256-wide output
// per row tile. Round-11's 391-block grid capped occupancy at 1.5 blocks/CU.
// This round: L1 gemm = 64-row M-tile x 8 waves (782 blocks, 40KB LDS ->
// ~3 resident blocks/CU, wave tile 32x64). L2/L3 unchanged from round 11.

#define DEVI __device__ __forceinline__

constexpr int NN    = 50000;
constexpr int EE    = 800000;
constexpr int RREL  = 8;
constexpr int NRSEG = NN * RREL;          // 400000
constexpr int NTC   = 1152;               // T cols = 9 groups x 128

using u16 = unsigned short;
using u32 = unsigned int;
using u64 = unsigned long long;

typedef short short8 __attribute__((ext_vector_type(8)));
typedef float f32x4  __attribute__((ext_vector_type(4)));

DEVI float bf2f(u32 u){ union{u32 i; float f;} x; x.i = u << 16; return x.f; }
DEVI u16   f2b(float f){ u32 u = __float_as_uint(f); u32 r = u + 0x7fffu + ((u >> 16) & 1u); return (u16)(r >> 16); }

typedef const __attribute__((address_space(1))) u32 gas_u32;
typedef __attribute__((address_space(3))) u32       las_u32;
DEVI void gload16(const void* g, void* l){
  __builtin_amdgcn_global_load_lds((gas_u32*)(u64)g, (las_u32*)(u64)l, 16, 0, 0);
}

// ---------------- prep kernels ----------------

__global__ void count_k(const int* __restrict__ dst, const int* __restrict__ et, int* __restrict__ cnt){
  int e = blockIdx.x * 256 + threadIdx.x;
  if(e < EE) atomicAdd(&cnt[dst[e] * RREL + et[e]], 1);
}

constexpr int SCAN_E = 8;
constexpr int CHUNK  = 2048;
constexpr int NB     = (NRSEG + CHUNK - 1) / CHUNK;   // 196

__global__ void scan1_k(const int* __restrict__ cnt, int* __restrict__ bsums){
  __shared__ int sm[256];
  int b = blockIdx.x, t = threadIdx.x;
  int base = b * CHUNK + t * SCAN_E;
  int s = 0;
  #pragma unroll
  for(int j = 0; j < SCAN_E; j++){ int i = base + j; s += (i < NRSEG) ? cnt[i] : 0; }
  sm[t] = s; __syncthreads();
  for(int off = 128; off > 0; off >>= 1){ if(t < off) sm[t] += sm[t + off]; __syncthreads(); }
  if(t == 0) bsums[b] = sm[0];
}

__global__ void scan2_k(int* __restrict__ bsums){
  __shared__ int sm[256];
  int t = threadIdx.x;
  int v = (t < NB) ? bsums[t] : 0;
  sm[t] = v; __syncthreads();
  for(int off = 1; off < 256; off <<= 1){
    int x = (t >= off) ? sm[t - off] : 0; __syncthreads();
    sm[t] += x; __syncthreads();
  }
  if(t < NB) bsums[t] = sm[t] - v;   // exclusive
}

__global__ void scan3_k(const int* __restrict__ cnt, const int* __restrict__ bsums, int* __restrict__ offs){
  __shared__ int sm[256];
  int b = blockIdx.x, t = threadIdx.x;
  int base = b * CHUNK + t * SCAN_E;
  int loc[SCAN_E]; int run = 0;
  #pragma unroll
  for(int j = 0; j < SCAN_E; j++){ int i = base + j; int c = (i < NRSEG) ? cnt[i] : 0; loc[j] = run; run += c; }
  sm[t] = run; __syncthreads();
  for(int off = 1; off < 256; off <<= 1){
    int x = (t >= off) ? sm[t - off] : 0; __syncthreads();
    sm[t] += x; __syncthreads();
  }
  int tb = bsums[b] + sm[t] - run;
  #pragma unroll
  for(int j = 0; j < SCAN_E; j++){ int i = base + j; if(i < NRSEG) offs[i] = tb + loc[j]; }
  if(b == 0 && t == 0) offs[NRSEG] = EE;
}

__global__ void inv_k(const int* __restrict__ cnt, float* __restrict__ inv){
  int i = blockIdx.x * 256 + threadIdx.x;
  if(i < NRSEG){ int c = cnt[i]; inv[i] = 1.0f / (float)(c > 0 ? c : 1); }
}

// single sorted edge array: spk[p] = (src << 3) | rel
__global__ void fill_k(const int* __restrict__ src, const int* __restrict__ dst, const int* __restrict__ et,
                       const int* __restrict__ offs, int* __restrict__ fill, int* __restrict__ spk){
  int e = blockIdx.x * 256 + threadIdx.x;
  if(e < EE){
    int d = dst[e], r = et[e];
    int seg = d * RREL + r;
    int i = atomicAdd(&fill[seg], 1);
    spk[offs[seg] + i] = (src[e] << 3) | r;
  }
}

__global__ void castx_k(const float* __restrict__ x, u16* __restrict__ xb){
  int i = blockIdx.x * 256 + threadIdx.x;
  if(i < NN * 128) xb[i] = f2b(x[i]);
}

// Wp[g][o][i] = bf16( g<R ? W[g][i][o] : root[i][o] )   (rows contiguous in fin)
__global__ void packw_k(const float* __restrict__ w, const float* __restrict__ root,
                        u16* __restrict__ wp, int FIN, int FOUT){
  int idx = blockIdx.x * 256 + threadIdx.x;
  int tot = (RREL + 1) * FIN * FOUT;
  if(idx < tot){
    int i = idx % FIN;
    int o = (idx / FIN) % FOUT;
    int g = idx / (FIN * FOUT);
    float v = (g < RREL) ? w[((size_t)g * FIN + i) * FOUT + o] : root[(size_t)i * FOUT + o];
    wp[idx] = f2b(v);
  }
}

// ---------------- aggregation (L1, input-side): 16-lane group per segment ----------------

DEVI void acc8(float* a, uint4 v){
  a[0] += bf2f(v.x & 0xffffu); a[1] += bf2f(v.x >> 16);
  a[2] += bf2f(v.y & 0xffffu); a[3] += bf2f(v.y >> 16);
  a[4] += bf2f(v.z & 0xffffu); a[5] += bf2f(v.z >> 16);
  a[6] += bf2f(v.w & 0xffffu); a[7] += bf2f(v.w >> 16);
}

DEVI void fma8(float* a, uint4 v, float c){
  a[0] += c * bf2f(v.x & 0xffffu); a[1] += c * bf2f(v.x >> 16);
  a[2] += c * bf2f(v.y & 0xffffu); a[3] += c * bf2f(v.y >> 16);
  a[4] += c * bf2f(v.z & 0xffffu); a[5] += c * bf2f(v.z >> 16);
  a[6] += c * bf2f(v.w & 0xffffu); a[7] += c * bf2f(v.w >> 16);
}

template<int FIN, int RSUB, int LDW>
__global__ __launch_bounds__(256)
void agg_k(const u16* __restrict__ hb, const int* __restrict__ spk,
           const int* __restrict__ offs, const float* __restrict__ inv,
           u16* __restrict__ agg, int r0)
{
  constexpr int G = FIN / 8;               // lanes per group
  const int gl  = threadIdx.x & (G - 1);
  int gid = (int)((blockIdx.x * blockDim.x + threadIdx.x) / G);
  const int ng = (int)((gridDim.x * blockDim.x) / G);
  const int S = NN * RSUB;
  for(int s = gid; s < S; s += ng){
    int n = s / RSUB, rr = s - n * RSUB;
    int seg = n * RREL + r0 + rr;
    int beg = offs[seg], end = offs[seg + 1];
    float sc = inv[seg];
    float acc[8];
    #pragma unroll
    for(int i = 0; i < 8; i++) acc[i] = 0.f;
    int e = beg;
    for(; e + 2 <= end; e += 2){
      int s0 = spk[e] >> 3, s1 = spk[e + 1] >> 3;
      uint4 v0 = ((const uint4*)(hb + (size_t)s0 * FIN))[gl];
      uint4 v1 = ((const uint4*)(hb + (size_t)s1 * FIN))[gl];
      acc8(acc, v0);
      acc8(acc, v1);
    }
    if(e < end){
      uint4 v0 = ((const uint4*)(hb + (size_t)(spk[e] >> 3) * FIN))[gl];
      acc8(acc, v0);
    }
    uint4 o;
    o.x = (u32)f2b(acc[0] * sc) | ((u32)f2b(acc[1] * sc) << 16);
    o.y = (u32)f2b(acc[2] * sc) | ((u32)f2b(acc[3] * sc) << 16);
    o.z = (u32)f2b(acc[4] * sc) | ((u32)f2b(acc[5] * sc) << 16);
    o.w = (u32)f2b(acc[6] * sc) | ((u32)f2b(acc[7] * sc) << 16);
    ((uint4*)(agg + (size_t)n * LDW + rr * FIN))[gl] = o;
  }
}

// ---------------- L1 GEMM: 64x256 tile, 8 waves (2M x 4N), BK=32, 2-buf dbuf ----------------
// A (agg groups + root) read ONCE per row; 782 blocks -> ~3 resident/CU.

template<int FIN, int NAGG>
__global__ __launch_bounds__(512)
void gemm_k(const u16* __restrict__ Aagg, const u16* __restrict__ Aroot,
            const u16* __restrict__ Wagg, const u16* __restrict__ Wroot,
            const float* __restrict__ bias, float* __restrict__ dout,
            u16* __restrict__ hbout)
{
  constexpr int KSG = FIN / 32;
  constexpr int NG  = NAGG + 1;
  constexpr int NKS = NG * KSG;          // 36
  constexpr int LDA = NAGG * FIN;        // 1024
  constexpr int ASL = 256;               // 64 rows x 4 slots
  constexpr int BSL = 1024;              // 256 rows x 4 slots
  __shared__ u16 lds[2][(ASL + BSL) * 8];   // 2 x 20KB
  const int bm  = (int)blockIdx.x;
  const int tid = threadIdx.x;
  const int wid = tid >> 6, lane = tid & 63;
  const int wm  = wid >> 2, wn = wid & 3;   // 2 x 4 waves, wave tile 32x64

  auto stage = [&](int ks, u16* l){
    u16* lA = l;
    u16* lB = l + ASL * 8;
    int g    = ks / KSG;
    int koff = (ks - g * KSG) * 32;
    bool isRoot = (g == NAGG);
    if(wid < 4){                          // A: slots 0..255
      int sb = wid * 64;
      int s  = sb + lane;
      int pair = s >> 3, cs = s & 7;
      int c    = cs ^ (pair & 7);
      int row  = pair * 2 + (c >> 2);     // 0..63
      int k8   = c & 3;
      int kk   = koff + k8 * 8;
      int rowg = bm * 64 + row; rowg = rowg < NN ? rowg : NN - 1;
      const u16* ga = isRoot ? (Aroot + (size_t)rowg * FIN + kk)
                             : (Aagg + (size_t)rowg * LDA + g * FIN + kk);
      gload16(ga, lA + sb * 8);
    }
    #pragma unroll
    for(int rnd = 0; rnd < 2; rnd++){     // B: slots 0..1023
      int sb = rnd * 512 + wid * 64;
      int s  = sb + lane;
      int pair = s >> 3, cs = s & 7;
      int c    = cs ^ (pair & 7);
      int row  = pair * 2 + (c >> 2);     // 0..255
      int k8   = c & 3;
      int kk   = koff + k8 * 8;
      const u16* gb = isRoot ? (Wroot + (size_t)row * FIN + kk)
                             : (Wagg + ((size_t)g * 256 + row) * FIN + kk);
      gload16(gb, lB + sb * 8);
    }
  };

  auto ldfrag = [&](const u16* buf, int row, int k8){
    int pair = row >> 1;
    int c    = ((row & 1) << 2) + k8;
    int cs   = c ^ (pair & 7);
    return *(const short8*)(buf + pair * 64 + cs * 8);
  };

  f32x4 acc[2][4] = {};

  stage(0, (u16*)lds[0]);
  __syncthreads();
  for(int ks = 0; ks < NKS; ks++){
    int cur = ks & 1;
    if(ks + 1 < NKS) stage(ks + 1, (u16*)lds[cur ^ 1]);
    const u16* lA = (const u16*)lds[cur];
    const u16* lB = lA + ASL * 8;
    short8 af[2], bf4[4];
    #pragma unroll
    for(int m = 0; m < 2; m++) af[m] = ldfrag(lA, wm * 32 + m * 16 + (lane & 15), lane >> 4);
    #pragma unroll
    for(int n = 0; n < 4; n++) bf4[n] = ldfrag(lB, wn * 64 + n * 16 + (lane & 15), lane >> 4);
    #pragma unroll
    for(int m = 0; m < 2; m++)
      #pragma unroll
      for(int n = 0; n < 4; n++)
        acc[m][n] = __builtin_amdgcn_mfma_f32_16x16x32_bf16(af[m], bf4[n], acc[m][n], 0, 0, 0);
    __syncthreads();
  }

  // epilogue; C/D layout: col = lane&15, row = (lane>>4)*4 + reg   [m89-verified]
  #pragma unroll
  for(int m = 0; m < 2; m++){
    #pragma unroll
    for(int j = 0; j < 4; j++){
      int grow = bm * 64 + wm * 32 + m * 16 + (lane >> 4) * 4 + j;
      if(grow >= NN) continue;
      #pragma unroll
      for(int n = 0; n < 4; n++){
        int gcol = wn * 64 + n * 16 + (lane & 15);
        float v = acc[m][n][j];
        v += bias[gcol];
        v = v > 0.f ? v : expm1f(v);
        dout[(size_t)grow * 512 + gcol] = v;
        hbout[(size_t)grow * 256 + gcol] = f2b(v);
      }
    }
  }
}

// ---------------- dense GEMM: T[n, jc*128+c] = sum_i A[n,i] * Bw[jc*128+c, i] ----------------

template<int FIN>
__global__ __launch_bounds__(512)
void dgemm_k(const u16* __restrict__ A, const u16* __restrict__ Bw, u16* __restrict__ T)
{
  constexpr int NKS = FIN / 32;
  constexpr int ASL = 512;
  constexpr int BSL = 512;
  constexpr int LPS = 2;
  __shared__ u16 lds[3][(ASL + BSL) * 8];
  const int bid = (int)blockIdx.x;
  const int bm  = bid / 9;
  const int jc  = bid % 9;
  const int tid = threadIdx.x;
  const int wid = tid >> 6, lane = tid & 63;
  const int wm  = wid >> 1, wn = wid & 1;      // 4x2 waves, wave tile 32x64

  auto stage = [&](int ks, u16* l){
    u16* lA = l;
    u16* lB = l + ASL * 8;
    int koff = ks * 32;
    {
      int sb = wid * 64;
      int s  = sb + lane;
      int pair = s >> 3, cs = s & 7;
      int c    = cs ^ (pair & 7);
      int row  = pair * 2 + (c >> 2);
      int k8   = c & 3;
      int kk   = koff + k8 * 8;
      int rowg = bm * 128 + row; rowg = rowg < NN ? rowg : NN - 1;
      gload16(A + (size_t)rowg * FIN + kk, lA + sb * 8);
    }
    {
      int sb = wid * 64;
      int s  = sb + lane;
      int pair = s >> 3, cs = s & 7;
      int c    = cs ^ (pair & 7);
      int row  = pair * 2 + (c >> 2);
      int k8   = c & 3;
      int kk   = koff + k8 * 8;
      gload16(Bw + ((size_t)(jc * 128 + row)) * FIN + kk, lB + sb * 8);
    }
  };

  auto ldfrag = [&](const u16* buf, int row, int k8){
    int pair = row >> 1;
    int c    = ((row & 1) << 2) + k8;
    int cs   = c ^ (pair & 7);
    return *(const short8*)(buf + pair * 64 + cs * 8);
  };

  f32x4 acc[2][4] = {};

  stage(0, (u16*)lds[0]);
  stage(1, (u16*)lds[1]);
  for(int ks = 0; ks < NKS; ks++){
    if(ks + 1 < NKS){
      asm volatile("s_waitcnt vmcnt(%0)" :: "i"(LPS) : "memory");
    } else {
      asm volatile("s_waitcnt vmcnt(0)" ::: "memory");
    }
    __builtin_amdgcn_sched_barrier(0);
    __builtin_amdgcn_s_barrier();
    __builtin_amdgcn_sched_barrier(0);
    if(ks + 2 < NKS) stage(ks + 2, (u16*)lds[(ks + 2) % 3]);
    const u16* lA = (const u16*)lds[ks % 3];
    const u16* lB = lA + ASL * 8;
    short8 af[2], bf4[4];
    #pragma unroll
    for(int m = 0; m < 2; m++) af[m] = ldfrag(lA, wm * 32 + m * 16 + (lane & 15), lane >> 4);
    #pragma unroll
    for(int n = 0; n < 4; n++) bf4[n] = ldfrag(lB, wn * 64 + n * 16 + (lane & 15), lane >> 4);
    #pragma unroll
    for(int m = 0; m < 2; m++)
      #pragma unroll
      for(int n = 0; n < 4; n++)
        acc[m][n] = __builtin_amdgcn_mfma_f32_16x16x32_bf16(af[m], bf4[n], acc[m][n], 0, 0, 0);
  }

  #pragma unroll
  for(int m = 0; m < 2; m++){
    #pragma unroll
    for(int j = 0; j < 4; j++){
      int grow = bm * 128 + wm * 32 + m * 16 + (lane >> 4) * 4 + j;
      if(grow >= NN) continue;
      #pragma unroll
      for(int n = 0; n < 4; n++){
        int gcol = wn * 64 + n * 16 + (lane & 15);
        T[(size_t)grow * NTC + jc * 128 + gcol] = f2b(acc[m][n][j]);
      }
    }
  }
}

// ---------------- scatter-mean (L2/L3, output-side): flat 8-unrolled loop ----------------

template<bool HB>
__global__ __launch_bounds__(256)
void scat_k(const u16* __restrict__ T, const int* __restrict__ spk,
            const int* __restrict__ offs, const float* __restrict__ inv,
            const float* __restrict__ bias, float* __restrict__ dout, int dcol0,
            u16* __restrict__ hbout)
{
  const int gl = threadIdx.x & 15;
  int n = (int)((blockIdx.x * 256 + threadIdx.x) >> 4);
  if(n >= NN) return;
  const float* invn = inv + n * RREL;
  float acc[8];
  { // root group at col 1024 (unscaled)
    uint4 v = *(const uint4*)(T + (size_t)n * NTC + 1024 + gl * 8);
    acc[0] = bf2f(v.x & 0xffffu); acc[1] = bf2f(v.x >> 16);
    acc[2] = bf2f(v.y & 0xffffu); acc[3] = bf2f(v.y >> 16);
    acc[4] = bf2f(v.z & 0xffffu); acc[5] = bf2f(v.z >> 16);
    acc[6] = bf2f(v.w & 0xffffu); acc[7] = bf2f(v.w >> 16);
  }
  int e  = offs[n * RREL];
  int e1 = offs[n * RREL + RREL];
  for(; e + 8 <= e1; e += 8){
    int p[8];
    #pragma unroll
    for(int j = 0; j < 8; j++) p[j] = spk[e + j];
    uint4 v[8];
    #pragma unroll
    for(int j = 0; j < 8; j++)
      v[j] = *(const uint4*)(T + (size_t)(p[j] >> 3) * NTC + (p[j] & 7) * 128 + gl * 8);
    #pragma unroll
    for(int j = 0; j < 8; j++) fma8(acc, v[j], invn[p[j] & 7]);
  }
  for(; e + 4 <= e1; e += 4){
    int p0 = spk[e], p1 = spk[e + 1], p2 = spk[e + 2], p3 = spk[e + 3];
    uint4 v0 = *(const uint4*)(T + (size_t)(p0 >> 3) * NTC + (p0 & 7) * 128 + gl * 8);
    uint4 v1 = *(const uint4*)(T + (size_t)(p1 >> 3) * NTC + (p1 & 7) * 128 + gl * 8);
    uint4 v2 = *(const uint4*)(T + (size_t)(p2 >> 3) * NTC + (p2 & 7) * 128 + gl * 8);
    uint4 v3 = *(const uint4*)(T + (size_t)(p3 >> 3) * NTC + (p3 & 7) * 128 + gl * 8);
    fma8(acc, v0, invn[p0 & 7]); fma8(acc, v1, invn[p1 & 7]);
    fma8(acc, v2, invn[p2 & 7]); fma8(acc, v3, invn[p3 & 7]);
  }
  for(; e < e1; e++){
    int p0 = spk[e];
    uint4 v0 = *(const uint4*)(T + (size_t)(p0 >> 3) * NTC + (p0 & 7) * 128 + gl * 8);
    fma8(acc, v0, invn[p0 & 7]);
  }
  float o[8];
  #pragma unroll
  for(int i = 0; i < 8; i++){
    float v = acc[i] + bias[gl * 8 + i];
    o[i] = v > 0.f ? v : expm1f(v);
  }
  float4* dp = (float4*)(dout + (size_t)n * 512 + dcol0 + gl * 8);
  dp[0] = make_float4(o[0], o[1], o[2], o[3]);
  dp[1] = make_float4(o[4], o[5], o[6], o[7]);
  if(HB){
    uint4 hv;
    hv.x = (u32)f2b(o[0]) | ((u32)f2b(o[1]) << 16);
    hv.y = (u32)f2b(o[2]) | ((u32)f2b(o[3]) << 16);
    hv.z = (u32)f2b(o[4]) | ((u32)f2b(o[5]) << 16);
    hv.w = (u32)f2b(o[6]) | ((u32)f2b(o[7]) << 16);
    *(uint4*)(hbout + (size_t)n * 128 + gl * 8) = hv;
  }
}

// ---------------- host ----------------

extern "C" void kernel_launch(void* const* d_in, const int* in_sizes, int n_in,
                              void* d_out, int out_size, void* d_ws, size_t ws_size,
                              hipStream_t stream)
{
  const float* x     = (const float*)d_in[0];
  const int*   ei    = (const int*)d_in[1];   // [2, E] int32
  const int*   et    = (const int*)d_in[2];   // [E]
  const float* w1    = (const float*)d_in[3];
  const float* root1 = (const float*)d_in[4];
  const float* b1    = (const float*)d_in[5];
  const float* w2    = (const float*)d_in[6];
  const float* root2 = (const float*)d_in[7];
  const float* b2    = (const float*)d_in[8];
  const float* w3    = (const float*)d_in[9];
  const float* root3 = (const float*)d_in[10];
  const float* b3    = (const float*)d_in[11];
  float* out = (float*)d_out;

  const int* esrc = ei;
  const int* edst = ei + EE;

  char* w = (char*)d_ws;
  auto alloc = [&](size_t bytes)->char*{ char* p = w; w += (bytes + 255) & ~(size_t)255; return p; };
  int*   cnt   = (int*)  alloc((size_t)NRSEG * 4);
  int*   offs  = (int*)  alloc((size_t)(NRSEG + 1) * 4);
  int*   fill  = (int*)  alloc((size_t)NRSEG * 4);
  float* inv   = (float*)alloc((size_t)NRSEG * 4);
  int*   spk   = (int*)  alloc((size_t)EE * 4);
  u16*   xb    = (u16*)  alloc((size_t)NN * 128 * 2);
  u16*   h1b   = (u16*)  alloc((size_t)NN * 256 * 2);
  u16*   h2b   = (u16*)  alloc((size_t)NN * 128 * 2);
  u16*   wp1   = (u16*)  alloc((size_t)9 * 256 * 128 * 2);
  u16*   wp2   = (u16*)  alloc((size_t)9 * 256 * 128 * 2);
  u16*   wp3   = (u16*)  alloc((size_t)9 * 128 * 128 * 2);
  int*   bsums = (int*)  alloc(1024 * 4);
  u16*   agg   = (u16*)  alloc((size_t)NN * 1024 * 2);   // L1 input-side agg
  u16*   T     = (u16*)  alloc((size_t)NN * NTC * 2);    // L2/L3 dense transform
  (void)ws_size; (void)in_sizes; (void)n_in; (void)out_size;

  hipMemsetAsync(cnt,  0, (size_t)NRSEG * 4, stream);
  hipMemsetAsync(fill, 0, (size_t)NRSEG * 4, stream);

  count_k<<<(EE + 255) / 256, 256, 0, stream>>>(edst, et, cnt);
  scan1_k<<<NB, 256, 0, stream>>>(cnt, bsums);
  scan2_k<<<1, 256, 0, stream>>>(bsums);
  scan3_k<<<NB, 256, 0, stream>>>(cnt, bsums, offs);
  inv_k<<<(NRSEG + 255) / 256, 256, 0, stream>>>(cnt, inv);
  fill_k<<<(EE + 255) / 256, 256, 0, stream>>>(esrc, edst, et, offs, fill, spk);
  castx_k<<<(NN * 128 + 255) / 256, 256, 0, stream>>>(x, xb);

  packw_k<<<(9 * 128 * 256 + 255) / 256, 256, 0, stream>>>(w1, root1, wp1, 128, 256);
  packw_k<<<(9 * 256 * 128 + 255) / 256, 256, 0, stream>>>(w2, root2, wp2, 256, 128);
  packw_k<<<(9 * 128 * 128 + 255) / 256, 256, 0, stream>>>(w3, root3, wp3, 128, 128);

  const int MT  = (NN + 127) / 128;       // 391
  const int MT2 = (NN + 63) / 64;         // 782
  const int SB  = (NN * 16 + 255) / 256;  // 3125 scatter blocks

  // Layer 1 (input-side): fin=128, fout=256, 64-row tiles
  agg_k<128, 8, 1024><<<4096, 256, 0, stream>>>(xb, spk, offs, inv, agg, 0);
  gemm_k<128, 8><<<MT2, 512, 0, stream>>>(
      agg, xb, wp1, wp1 + (size_t)8 * 256 * 128, b1, out, h1b);

  // Layer 2 (output-side): T2 = h1 @ wp2^T [N,1152], then flat scatter-mean
  dgemm_k<256><<<MT * 9, 512, 0, stream>>>(h1b, wp2, T);
  scat_k<true><<<SB, 256, 0, stream>>>(T, spk, offs, inv, b2, out, 256, h2b);

  // Layer 3 (output-side): T3 = h2 @ wp3^T [N,1152], then flat scatter-mean
  dgemm_k<128><<<MT * 9, 512, 0, stream>>>(h2b, wp3, T);
  scat_k<false><<<SB, 256, 0, stream>>>(T, spk, offs, inv, b3, out, 384, nullptr);
}

// Round 14
// 423.127 us; speedup vs baseline: 1.0307x; 1.0307x over previous
//
#include <hip/hip_runtime.h>

// R-GCN (3 layers) on MI355X — Round 14.
// L1 = dgemm-shape (128x128 tiles, 8 waves, 3-buf counted-vmcnt, 782 blocks)
// with XCD-PAIRED swizzle: the two jc column-halves of each 128-row panel
// land on the same XCD in adjacent dispatch slots, so the A panel is L2-hot
// for the second block (fixes round-12's doubled FETCH).
// Prep fused: inv into scan3; castx+packw1+packw2+packw3 into one kernel.
// L2/L3 output-side (dgemm -> T -> flat scat) unchanged from round 11.

#define DEVI __device__ __forceinline__

constexpr int NN    = 50000;
constexpr int EE    = 800000;
constexpr int RREL  = 8;
constexpr int NRSEG = NN * RREL;          // 400000
constexpr int NTC   = 1152;               // 9 groups x 128
constexpr int MT1   = (NN + 127) / 128;   // 391 row panels

using u16 = unsigned short;
using u32 = unsigned int;
using u64 = unsigned long long;

typedef short short8 __attribute__((ext_vector_type(8)));
typedef float f32x4  __attribute__((ext_vector_type(4)));

DEVI float bf2f(u32 u){ union{u32 i; float f;} x; x.i = u << 16; return x.f; }
DEVI u16   f2b(float f){ u32 u = __float_as_uint(f); u32 r = u + 0x7fffu + ((u >> 16) & 1u); return (u16)(r >> 16); }

typedef const __attribute__((address_space(1))) u32 gas_u32;
typedef __attribute__((address_space(3))) u32       las_u32;
DEVI void gload16(const void* g, void* l){
  __builtin_amdgcn_global_load_lds((gas_u32*)(u64)g, (las_u32*)(u64)l, 16, 0, 0);
}

// ---------------- prep kernels ----------------

__global__ void count_k(const int* __restrict__ dst, const int* __restrict__ et, int* __restrict__ cnt){
  int e = blockIdx.x * 256 + threadIdx.x;
  if(e < EE) atomicAdd(&cnt[dst[e] * RREL + et[e]], 1);
}

constexpr int SCAN_E = 8;
constexpr int CHUNK  = 2048;
constexpr int NB     = (NRSEG + CHUNK - 1) / CHUNK;   // 196

__global__ void scan1_k(const int* __restrict__ cnt, int* __restrict__ bsums){
  __shared__ int sm[256];
  int b = blockIdx.x, t = threadIdx.x;
  int base = b * CHUNK + t * SCAN_E;
  int s = 0;
  #pragma unroll
  for(int j = 0; j < SCAN_E; j++){ int i = base + j; s += (i < NRSEG) ? cnt[i] : 0; }
  sm[t] = s; __syncthreads();
  for(int off = 128; off > 0; off >>= 1){ if(t < off) sm[t] += sm[t + off]; __syncthreads(); }
  if(t == 0) bsums[b] = sm[0];
}

__global__ void scan2_k(int* __restrict__ bsums){
  __shared__ int sm[256];
  int t = threadIdx.x;
  int v = (t < NB) ? bsums[t] : 0;
  sm[t] = v; __syncthreads();
  for(int off = 1; off < 256; off <<= 1){
    int x = (t >= off) ? sm[t - off] : 0; __syncthreads();
    sm[t] += x; __syncthreads();
  }
  if(t < NB) bsums[t] = sm[t] - v;   // exclusive
}

// scan3 + inv fused (reads cnt anyway)
__global__ void scan3i_k(const int* __restrict__ cnt, const int* __restrict__ bsums,
                         int* __restrict__ offs, float* __restrict__ inv){
  __shared__ int sm[256];
  int b = blockIdx.x, t = threadIdx.x;
  int base = b * CHUNK + t * SCAN_E;
  int loc[SCAN_E]; int cv[SCAN_E]; int run = 0;
  #pragma unroll
  for(int j = 0; j < SCAN_E; j++){
    int i = base + j; int c = (i < NRSEG) ? cnt[i] : 0;
    cv[j] = c; loc[j] = run; run += c;
  }
  sm[t] = run; __syncthreads();
  for(int off = 1; off < 256; off <<= 1){
    int x = (t >= off) ? sm[t - off] : 0; __syncthreads();
    sm[t] += x; __syncthreads();
  }
  int tb = bsums[b] + sm[t] - run;
  #pragma unroll
  for(int j = 0; j < SCAN_E; j++){
    int i = base + j;
    if(i < NRSEG){
      offs[i] = tb + loc[j];
      inv[i]  = 1.0f / (float)(cv[j] > 0 ? cv[j] : 1);
    }
  }
  if(b == 0 && t == 0) offs[NRSEG] = EE;
}

// single sorted edge array: spk[p] = (src << 3) | rel
__global__ void fill_k(const int* __restrict__ src, const int* __restrict__ dst, const int* __restrict__ et,
                       const int* __restrict__ offs, int* __restrict__ fill, int* __restrict__ spk){
  int e = blockIdx.x * 256 + threadIdx.x;
  if(e < EE){
    int d = dst[e], r = et[e];
    int seg = d * RREL + r;
    int i = atomicAdd(&fill[seg], 1);
    spk[offs[seg] + i] = (src[e] << 3) | r;
  }
}

// fused: castx (xb + agg2 root cols) | wpL1 [256][1152] | wp2 | wp3
constexpr int PR0 = NN * 128;          // castx
constexpr int PR1 = 256 * NTC;         // wpL1
constexpr int PR2 = 9 * 256 * 128;     // wp2
constexpr int PR3 = 9 * 128 * 128;     // wp3
constexpr int PRT = PR0 + PR1 + PR2 + PR3;

__global__ void prep_pack_k(const float* __restrict__ x, u16* __restrict__ xb, u16* __restrict__ agg2,
                            const float* __restrict__ w1, const float* __restrict__ root1, u16* __restrict__ wpL1,
                            const float* __restrict__ w2, const float* __restrict__ root2, u16* __restrict__ wp2,
                            const float* __restrict__ w3, const float* __restrict__ root3, u16* __restrict__ wp3){
  int idx = blockIdx.x * 256 + threadIdx.x;
  if(idx < PR0){
    u16 v = f2b(x[idx]);
    xb[idx] = v;
    int n = idx >> 7, c = idx & 127;
    agg2[(size_t)n * NTC + 1024 + c] = v;
    return;
  }
  idx -= PR0;
  if(idx < PR1){
    int o = idx / NTC, k = idx % NTC;
    int g = k >> 7, i = k & 127;
    float v = (g < RREL) ? w1[((size_t)g * 128 + i) * 256 + o] : root1[(size_t)i * 256 + o];
    wpL1[idx] = f2b(v);
    return;
  }
  idx -= PR1;
  if(idx < PR2){
    int i = idx % 256;
    int o = (idx / 256) % 128;
    int g = idx / (256 * 128);
    float v = (g < RREL) ? w2[((size_t)g * 256 + i) * 128 + o] : root2[(size_t)i * 128 + o];
    wp2[idx] = f2b(v);
    return;
  }
  idx -= PR2;
  if(idx < PR3){
    int i = idx % 128;
    int o = (idx / 128) % 128;
    int g = idx / (128 * 128);
    float v = (g < RREL) ? w3[((size_t)g * 128 + i) * 128 + o] : root3[(size_t)i * 128 + o];
    wp3[idx] = f2b(v);
  }
}

// ---------------- aggregation (L1, input-side): 16-lane group per segment ----------------

DEVI void acc8(float* a, uint4 v){
  a[0] += bf2f(v.x & 0xffffu); a[1] += bf2f(v.x >> 16);
  a[2] += bf2f(v.y & 0xffffu); a[3] += bf2f(v.y >> 16);
  a[4] += bf2f(v.z & 0xffffu); a[5] += bf2f(v.z >> 16);
  a[6] += bf2f(v.w & 0xffffu); a[7] += bf2f(v.w >> 16);
}

DEVI void fma8(float* a, uint4 v, float c){
  a[0] += c * bf2f(v.x & 0xffffu); a[1] += c * bf2f(v.x >> 16);
  a[2] += c * bf2f(v.y & 0xffffu); a[3] += c * bf2f(v.y >> 16);
  a[4] += c * bf2f(v.z & 0xffffu); a[5] += c * bf2f(v.z >> 16);
  a[6] += c * bf2f(v.w & 0xffffu); a[7] += c * bf2f(v.w >> 16);
}

template<int FIN, int RSUB, int LDW>
__global__ __launch_bounds__(256)
void agg_k(const u16* __restrict__ hb, const int* __restrict__ spk,
           const int* __restrict__ offs, const float* __restrict__ inv,
           u16* __restrict__ agg, int r0)
{
  constexpr int G = FIN / 8;
  const int gl  = threadIdx.x & (G - 1);
  int gid = (int)((blockIdx.x * blockDim.x + threadIdx.x) / G);
  const int ng = (int)((gridDim.x * blockDim.x) / G);
  const int S = NN * RSUB;
  for(int s = gid; s < S; s += ng){
    int n = s / RSUB, rr = s - n * RSUB;
    int seg = n * RREL + r0 + rr;
    int beg = offs[seg], end = offs[seg + 1];
    float sc = inv[seg];
    float acc[8];
    #pragma unroll
    for(int i = 0; i < 8; i++) acc[i] = 0.f;
    int e = beg;
    for(; e + 2 <= end; e += 2){
      int s0 = spk[e] >> 3, s1 = spk[e + 1] >> 3;
      uint4 v0 = ((const uint4*)(hb + (size_t)s0 * FIN))[gl];
      uint4 v1 = ((const uint4*)(hb + (size_t)s1 * FIN))[gl];
      acc8(acc, v0);
      acc8(acc, v1);
    }
    if(e < end){
      uint4 v0 = ((const uint4*)(hb + (size_t)(spk[e] >> 3) * FIN))[gl];
      acc8(acc, v0);
    }
    uint4 o;
    o.x = (u32)f2b(acc[0] * sc) | ((u32)f2b(acc[1] * sc) << 16);
    o.y = (u32)f2b(acc[2] * sc) | ((u32)f2b(acc[3] * sc) << 16);
    o.z = (u32)f2b(acc[4] * sc) | ((u32)f2b(acc[5] * sc) << 16);
    o.w = (u32)f2b(acc[6] * sc) | ((u32)f2b(acc[7] * sc) << 16);
    ((uint4*)(agg + (size_t)n * LDW + rr * FIN))[gl] = o;
  }
}

// ---------------- unified GEMM: 128x128 out-tile, 8 waves, 3-buf counted-vmcnt ----------------
// A[n][K], Bw[col][K] both K-row-major.
// SWZ=0: bm = bid/NJC, jc = bid%NJC.
// SWZ=1 (L1): grid 8*ceil(2*MT1/8... = 784): xcd=bid&7, s=bid>>3, jc=s&1,
//             bm=xcd+8*(s>>1)  -> jc pair of one panel on SAME XCD, adjacent.
// EPI=0: T store (bf16). EPI=1: bias+ELU -> dout(512-stride)+hbout(256).

template<int K, int NJC, int EPI, int SWZ>
__global__ __launch_bounds__(512)
void dgemm_k(const u16* __restrict__ A, const u16* __restrict__ Bw,
             u16* __restrict__ T, const float* __restrict__ bias,
             float* __restrict__ dout, u16* __restrict__ hbout)
{
  constexpr int NKS = K / 32;
  constexpr int ASL = 512;
  constexpr int BSL = 512;
  constexpr int LPS = 2;
  __shared__ u16 lds[3][(ASL + BSL) * 8];
  int bm, jc;
  if constexpr(SWZ == 1){
    int d = (int)blockIdx.x;
    int x = d & 7, s = d >> 3;
    jc = s & 1;
    bm = x + 8 * (s >> 1);
    if(bm >= MT1) return;
  } else {
    bm = (int)blockIdx.x / NJC;
    jc = (int)blockIdx.x % NJC;
  }
  const int tid = threadIdx.x;
  const int wid = tid >> 6, lane = tid & 63;
  const int wm  = wid >> 1, wn = wid & 1;      // 4x2 waves, wave tile 32x64

  auto stage = [&](int ks, u16* l){
    u16* lA = l;
    u16* lB = l + ASL * 8;
    int koff = ks * 32;
    {
      int sb = wid * 64;
      int s  = sb + lane;
      int pair = s >> 3, cs = s & 7;
      int c    = cs ^ (pair & 7);
      int row  = pair * 2 + (c >> 2);
      int k8   = c & 3;
      int kk   = koff + k8 * 8;
      int rowg = bm * 128 + row; rowg = rowg < NN ? rowg : NN - 1;
      gload16(A + (size_t)rowg * K + kk, lA + sb * 8);
    }
    {
      int sb = wid * 64;
      int s  = sb + lane;
      int pair = s >> 3, cs = s & 7;
      int c    = cs ^ (pair & 7);
      int row  = pair * 2 + (c >> 2);
      int k8   = c & 3;
      int kk   = koff + k8 * 8;
      gload16(Bw + ((size_t)(jc * 128 + row)) * K + kk, lB + sb * 8);
    }
  };

  auto ldfrag = [&](const u16* buf, int row, int k8){
    int pair = row >> 1;
    int c    = ((row & 1) << 2) + k8;
    int cs   = c ^ (pair & 7);
    return *(const short8*)(buf + pair * 64 + cs * 8);
  };

  f32x4 acc[2][4] = {};

  stage(0, (u16*)lds[0]);
  stage(1, (u16*)lds[1]);
  for(int ks = 0; ks < NKS; ks++){
    if(ks + 1 < NKS){
      asm volatile("s_waitcnt vmcnt(%0)" :: "i"(LPS) : "memory");
    } else {
      asm volatile("s_waitcnt vmcnt(0)" ::: "memory");
    }
    __builtin_amdgcn_sched_barrier(0);
    __builtin_amdgcn_s_barrier();
    __builtin_amdgcn_sched_barrier(0);
    if(ks + 2 < NKS) stage(ks + 2, (u16*)lds[(ks + 2) % 3]);
    const u16* lA = (const u16*)lds[ks % 3];
    const u16* lB = lA + ASL * 8;
    short8 af[2], bf4[4];
    #pragma unroll
    for(int m = 0; m < 2; m++) af[m] = ldfrag(lA, wm * 32 + m * 16 + (lane & 15), lane >> 4);
    #pragma unroll
    for(int n = 0; n < 4; n++) bf4[n] = ldfrag(lB, wn * 64 + n * 16 + (lane & 15), lane >> 4);
    #pragma unroll
    for(int m = 0; m < 2; m++)
      #pragma unroll
      for(int n = 0; n < 4; n++)
        acc[m][n] = __builtin_amdgcn_mfma_f32_16x16x32_bf16(af[m], bf4[n], acc[m][n], 0, 0, 0);
  }

  // epilogue; C/D layout: col = lane&15, row = (lane>>4)*4 + reg   [m89-verified]
  #pragma unroll
  for(int m = 0; m < 2; m++){
    #pragma unroll
    for(int j = 0; j < 4; j++){
      int grow = bm * 128 + wm * 32 + m * 16 + (lane >> 4) * 4 + j;
      if(grow >= NN) continue;
      #pragma unroll
      for(int n = 0; n < 4; n++){
        int lcol = wn * 64 + n * 16 + (lane & 15);
        if constexpr(EPI == 0){
          T[(size_t)grow * NTC + jc * 128 + lcol] = f2b(acc[m][n][j]);
        } else {
          int gcol = jc * 128 + lcol;
          float v = acc[m][n][j] + bias[gcol];
          v = v > 0.f ? v : expm1f(v);
          dout[(size_t)grow * 512 + gcol] = v;
          hbout[(size_t)grow * 256 + gcol] = f2b(v);
        }
      }
    }
  }
}

// ---------------- scatter-mean (L2/L3, output-side): flat 8-unrolled loop ----------------

template<bool HB>
__global__ __launch_bounds__(256)
void scat_k(const u16* __restrict__ T, const int* __restrict__ spk,
            const int* __restrict__ offs, const float* __restrict__ inv,
            const float* __restrict__ bias, float* __restrict__ dout, int dcol0,
            u16* __restrict__ hbout)
{
  const int gl = threadIdx.x & 15;
  int n = (int)((blockIdx.x * 256 + threadIdx.x) >> 4);
  if(n >= NN) return;
  const float* invn = inv + n * RREL;
  float acc[8];
  { // root group at col 1024 (unscaled)
    uint4 v = *(const uint4*)(T + (size_t)n * NTC + 1024 + gl * 8);
    acc[0] = bf2f(v.x & 0xffffu); acc[1] = bf2f(v.x >> 16);
    acc[2] = bf2f(v.y & 0xffffu); acc[3] = bf2f(v.y >> 16);
    acc[4] = bf2f(v.z & 0xffffu); acc[5] = bf2f(v.z >> 16);
    acc[6] = bf2f(v.w & 0xffffu); acc[7] = bf2f(v.w >> 16);
  }
  int e  = offs[n * RREL];
  int e1 = offs[n * RREL + RREL];
  for(; e + 8 <= e1; e += 8){
    int p[8];
    #pragma unroll
    for(int j = 0; j < 8; j++) p[j] = spk[e + j];
    uint4 v[8];
    #pragma unroll
    for(int j = 0; j < 8; j++)
      v[j] = *(const uint4*)(T + (size_t)(p[j] >> 3) * NTC + (p[j] & 7) * 128 + gl * 8);
    #pragma unroll
    for(int j = 0; j < 8; j++) fma8(acc, v[j], invn[p[j] & 7]);
  }
  for(; e + 4 <= e1; e += 4){
    int p0 = spk[e], p1 = spk[e + 1], p2 = spk[e + 2], p3 = spk[e + 3];
    uint4 v0 = *(const uint4*)(T + (size_t)(p0 >> 3) * NTC + (p0 & 7) * 128 + gl * 8);
    uint4 v1 = *(const uint4*)(T + (size_t)(p1 >> 3) * NTC + (p1 & 7) * 128 + gl * 8);
    uint4 v2 = *(const uint4*)(T + (size_t)(p2 >> 3) * NTC + (p2 & 7) * 128 + gl * 8);
    uint4 v3 = *(const uint4*)(T + (size_t)(p3 >> 3) * NTC + (p3 & 7) * 128 + gl * 8);
    fma8(acc, v0, invn[p0 & 7]); fma8(acc, v1, invn[p1 & 7]);
    fma8(acc, v2, invn[p2 & 7]); fma8(acc, v3, invn[p3 & 7]);
  }
  for(; e < e1; e++){
    int p0 = spk[e];
    uint4 v0 = *(const uint4*)(T + (size_t)(p0 >> 3) * NTC + (p0 & 7) * 128 + gl * 8);
    fma8(acc, v0, invn[p0 & 7]);
  }
  float o[8];
  #pragma unroll
  for(int i = 0; i < 8; i++){
    float v = acc[i] + bias[gl * 8 + i];
    o[i] = v > 0.f ? v : expm1f(v);
  }
  float4* dp = (float4*)(dout + (size_t)n * 512 + dcol0 + gl * 8);
  dp[0] = make_float4(o[0], o[1], o[2], o[3]);
  dp[1] = make_float4(o[4], o[5], o[6], o[7]);
  if(HB){
    uint4 hv;
    hv.x = (u32)f2b(o[0]) | ((u32)f2b(o[1]) << 16);
    hv.y = (u32)f2b(o[2]) | ((u32)f2b(o[3]) << 16);
    hv.z = (u32)f2b(o[4]) | ((u32)f2b(o[5]) << 16);
    hv.w = (u32)f2b(o[6]) | ((u32)f2b(o[7]) << 16);
    *(uint4*)(hbout + (size_t)n * 128 + gl * 8) = hv;
  }
}

// ---------------- host ----------------

extern "C" void kernel_launch(void* const* d_in, const int* in_sizes, int n_in,
                              void* d_out, int out_size, void* d_ws, size_t ws_size,
                              hipStream_t stream)
{
  const float* x     = (const float*)d_in[0];
  const int*   ei    = (const int*)d_in[1];   // [2, E] int32
  const int*   et    = (const int*)d_in[2];   // [E]
  const float* w1    = (const float*)d_in[3];
  const float* root1 = (const float*)d_in[4];
  const float* b1    = (const float*)d_in[5];
  const float* w2    = (const float*)d_in[6];
  const float* root2 = (const float*)d_in[7];
  const float* b2    = (const float*)d_in[8];
  const float* w3    = (const float*)d_in[9];
  const float* root3 = (const float*)d_in[10];
  const float* b3    = (const float*)d_in[11];
  float* out = (float*)d_out;

  const int* esrc = ei;
  const int* edst = ei + EE;

  char* w = (char*)d_ws;
  auto alloc = [&](size_t bytes)->char*{ char* p = w; w += (bytes + 255) & ~(size_t)255; return p; };
  int*   cnt   = (int*)  alloc((size_t)NRSEG * 4);
  int*   offs  = (int*)  alloc((size_t)(NRSEG + 1) * 4);
  int*   fill  = (int*)  alloc((size_t)NRSEG * 4);
  float* inv   = (float*)alloc((size_t)NRSEG * 4);
  int*   spk   = (int*)  alloc((size_t)EE * 4);
  u16*   xb    = (u16*)  alloc((size_t)NN * 128 * 2);
  u16*   h1b   = (u16*)  alloc((size_t)NN * 256 * 2);
  u16*   h2b   = (u16*)  alloc((size_t)NN * 128 * 2);
  u16*   wpL1  = (u16*)  alloc((size_t)256 * NTC * 2);   // [256][1152]
  u16*   wp2   = (u16*)  alloc((size_t)9 * 256 * 128 * 2);
  u16*   wp3   = (u16*)  alloc((size_t)9 * 128 * 128 * 2);
  int*   bsums = (int*)  alloc(1024 * 4);
  u16*   agg2  = (u16*)  alloc((size_t)NN * NTC * 2);    // [N,1152]: 8 agg groups + x
  u16*   T     = (u16*)  alloc((size_t)NN * NTC * 2);    // L2/L3 dense transform
  (void)ws_size; (void)in_sizes; (void)n_in; (void)out_size;

  hipMemsetAsync(cnt,  0, (size_t)NRSEG * 4, stream);
  hipMemsetAsync(fill, 0, (size_t)NRSEG * 4, stream);

  count_k<<<(EE + 255) / 256, 256, 0, stream>>>(edst, et, cnt);
  scan1_k<<<NB, 256, 0, stream>>>(cnt, bsums);
  scan2_k<<<1, 256, 0, stream>>>(bsums);
  scan3i_k<<<NB, 256, 0, stream>>>(cnt, bsums, offs, inv);
  fill_k<<<(EE + 255) / 256, 256, 0, stream>>>(esrc, edst, et, offs, fill, spk);
  prep_pack_k<<<(PRT + 255) / 256, 256, 0, stream>>>(
      x, xb, agg2, w1, root1, wpL1, w2, root2, wp2, w3, root3, wp3);

  const int MT = (NN + 127) / 128;       // 391
  const int SB = (NN * 16 + 255) / 256;  // 3125 scatter blocks

  // Layer 1 (input-side agg, XCD-paired dgemm): K=1152, 2 col groups
  agg_k<128, 8, NTC><<<4096, 256, 0, stream>>>(xb, spk, offs, inv, agg2, 0);
  dgemm_k<NTC, 2, 1, 1><<<784, 512, 0, stream>>>(agg2, wpL1, nullptr, b1, out, h1b);

  // Layer 2 (output-side): T2 = h1 @ wp2^T [N,1152], then flat scatter-mean
  dgemm_k<256, 9, 0, 0><<<MT * 9, 512, 0, stream>>>(h1b, wp2, T, nullptr, nullptr, nullptr);
  scat_k<true><<<SB, 256, 0, stream>>>(T, spk, offs, inv, b2, out, 256, h2b);

  // Layer 3 (output-side): T3 = h2 @ wp3^T [N,1152], then flat scatter-mean
  dgemm_k<128, 9, 0, 0><<<MT * 9, 512, 0, stream>>>(h2b, wp3, T, nullptr, nullptr, nullptr);
  scat_k<false><<<SB, 256, 0, stream>>>(T, spk, offs, inv, b3, out, 384, nullptr);
}

// Round 15
// 411.020 us; speedup vs baseline: 1.0610x; 1.0295x over previous
//
#include <hip/hip_runtime.h>

// R-GCN (3 layers) on MI355X — Round 15.
// L1 dgemm was latency-bound (1.95 TB/s, MfmaUtil 15%): agg2 reads are
// cross-XCD L3 hits (~500cyc) and the 3-buf pipeline covers only ~2 K-steps.
// (1) L1 pipeline deepened to DEPTH=4 (prefetch-3, vmcnt(4) steady state,
//     64KB LDS). (2) Root K-block (ks>=32) read directly from hot xb
//     (agg2 shrinks to [N,1024]). L2/L3 keep DEPTH=3. Rest = round 14.

#define DEVI __device__ __forceinline__

constexpr int NN    = 50000;
constexpr int EE    = 800000;
constexpr int RREL  = 8;
constexpr int NRSEG = NN * RREL;          // 400000
constexpr int NTC   = 1152;               // 9 groups x 128
constexpr int MT1   = (NN + 127) / 128;   // 391 row panels

using u16 = unsigned short;
using u32 = unsigned int;
using u64 = unsigned long long;

typedef short short8 __attribute__((ext_vector_type(8)));
typedef float f32x4  __attribute__((ext_vector_type(4)));

DEVI float bf2f(u32 u){ union{u32 i; float f;} x; x.i = u << 16; return x.f; }
DEVI u16   f2b(float f){ u32 u = __float_as_uint(f); u32 r = u + 0x7fffu + ((u >> 16) & 1u); return (u16)(r >> 16); }

typedef const __attribute__((address_space(1))) u32 gas_u32;
typedef __attribute__((address_space(3))) u32       las_u32;
DEVI void gload16(const void* g, void* l){
  __builtin_amdgcn_global_load_lds((gas_u32*)(u64)g, (las_u32*)(u64)l, 16, 0, 0);
}

// ---------------- prep kernels ----------------

__global__ void count_k(const int* __restrict__ dst, const int* __restrict__ et, int* __restrict__ cnt){
  int e = blockIdx.x * 256 + threadIdx.x;
  if(e < EE) atomicAdd(&cnt[dst[e] * RREL + et[e]], 1);
}

constexpr int SCAN_E = 8;
constexpr int CHUNK  = 2048;
constexpr int NB     = (NRSEG + CHUNK - 1) / CHUNK;   // 196

__global__ void scan1_k(const int* __restrict__ cnt, int* __restrict__ bsums){
  __shared__ int sm[256];
  int b = blockIdx.x, t = threadIdx.x;
  int base = b * CHUNK + t * SCAN_E;
  int s = 0;
  #pragma unroll
  for(int j = 0; j < SCAN_E; j++){ int i = base + j; s += (i < NRSEG) ? cnt[i] : 0; }
  sm[t] = s; __syncthreads();
  for(int off = 128; off > 0; off >>= 1){ if(t < off) sm[t] += sm[t + off]; __syncthreads(); }
  if(t == 0) bsums[b] = sm[0];
}

__global__ void scan2_k(int* __restrict__ bsums){
  __shared__ int sm[256];
  int t = threadIdx.x;
  int v = (t < NB) ? bsums[t] : 0;
  sm[t] = v; __syncthreads();
  for(int off = 1; off < 256; off <<= 1){
    int x = (t >= off) ? sm[t - off] : 0; __syncthreads();
    sm[t] += x; __syncthreads();
  }
  if(t < NB) bsums[t] = sm[t] - v;   // exclusive
}

// scan3 + inv fused
__global__ void scan3i_k(const int* __restrict__ cnt, const int* __restrict__ bsums,
                         int* __restrict__ offs, float* __restrict__ inv){
  __shared__ int sm[256];
  int b = blockIdx.x, t = threadIdx.x;
  int base = b * CHUNK + t * SCAN_E;
  int loc[SCAN_E]; int cv[SCAN_E]; int run = 0;
  #pragma unroll
  for(int j = 0; j < SCAN_E; j++){
    int i = base + j; int c = (i < NRSEG) ? cnt[i] : 0;
    cv[j] = c; loc[j] = run; run += c;
  }
  sm[t] = run; __syncthreads();
  for(int off = 1; off < 256; off <<= 1){
    int x = (t >= off) ? sm[t - off] : 0; __syncthreads();
    sm[t] += x; __syncthreads();
  }
  int tb = bsums[b] + sm[t] - run;
  #pragma unroll
  for(int j = 0; j < SCAN_E; j++){
    int i = base + j;
    if(i < NRSEG){
      offs[i] = tb + loc[j];
      inv[i]  = 1.0f / (float)(cv[j] > 0 ? cv[j] : 1);
    }
  }
  if(b == 0 && t == 0) offs[NRSEG] = EE;
}

// single sorted edge array: spk[p] = (src << 3) | rel
__global__ void fill_k(const int* __restrict__ src, const int* __restrict__ dst, const int* __restrict__ et,
                       const int* __restrict__ offs, int* __restrict__ fill, int* __restrict__ spk){
  int e = blockIdx.x * 256 + threadIdx.x;
  if(e < EE){
    int d = dst[e], r = et[e];
    int seg = d * RREL + r;
    int i = atomicAdd(&fill[seg], 1);
    spk[offs[seg] + i] = (src[e] << 3) | r;
  }
}

// fused: castx (xb only) | wpL1 [256][1152] | wp2 | wp3
constexpr int PR0 = NN * 128;
constexpr int PR1 = 256 * NTC;
constexpr int PR2 = 9 * 256 * 128;
constexpr int PR3 = 9 * 128 * 128;
constexpr int PRT = PR0 + PR1 + PR2 + PR3;

__global__ void prep_pack_k(const float* __restrict__ x, u16* __restrict__ xb,
                            const float* __restrict__ w1, const float* __restrict__ root1, u16* __restrict__ wpL1,
                            const float* __restrict__ w2, const float* __restrict__ root2, u16* __restrict__ wp2,
                            const float* __restrict__ w3, const float* __restrict__ root3, u16* __restrict__ wp3){
  int idx = blockIdx.x * 256 + threadIdx.x;
  if(idx < PR0){
    xb[idx] = f2b(x[idx]);
    return;
  }
  idx -= PR0;
  if(idx < PR1){
    int o = idx / NTC, k = idx % NTC;
    int g = k >> 7, i = k & 127;
    float v = (g < RREL) ? w1[((size_t)g * 128 + i) * 256 + o] : root1[(size_t)i * 256 + o];
    wpL1[idx] = f2b(v);
    return;
  }
  idx -= PR1;
  if(idx < PR2){
    int i = idx % 256;
    int o = (idx / 256) % 128;
    int g = idx / (256 * 128);
    float v = (g < RREL) ? w2[((size_t)g * 256 + i) * 128 + o] : root2[(size_t)i * 128 + o];
    wp2[idx] = f2b(v);
    return;
  }
  idx -= PR2;
  if(idx < PR3){
    int i = idx % 128;
    int o = (idx / 128) % 128;
    int g = idx / (128 * 128);
    float v = (g < RREL) ? w3[((size_t)g * 128 + i) * 128 + o] : root3[(size_t)i * 128 + o];
    wp3[idx] = f2b(v);
  }
}

// ---------------- aggregation (L1, input-side): 16-lane group per segment ----------------

DEVI void acc8(float* a, uint4 v){
  a[0] += bf2f(v.x & 0xffffu); a[1] += bf2f(v.x >> 16);
  a[2] += bf2f(v.y & 0xffffu); a[3] += bf2f(v.y >> 16);
  a[4] += bf2f(v.z & 0xffffu); a[5] += bf2f(v.z >> 16);
  a[6] += bf2f(v.w & 0xffffu); a[7] += bf2f(v.w >> 16);
}

DEVI void fma8(float* a, uint4 v, float c){
  a[0] += c * bf2f(v.x & 0xffffu); a[1] += c * bf2f(v.x >> 16);
  a[2] += c * bf2f(v.y & 0xffffu); a[3] += c * bf2f(v.y >> 16);
  a[4] += c * bf2f(v.z & 0xffffu); a[5] += c * bf2f(v.z >> 16);
  a[6] += c * bf2f(v.w & 0xffffu); a[7] += c * bf2f(v.w >> 16);
}

template<int FIN, int RSUB, int LDW>
__global__ __launch_bounds__(256)
void agg_k(const u16* __restrict__ hb, const int* __restrict__ spk,
           const int* __restrict__ offs, const float* __restrict__ inv,
           u16* __restrict__ agg, int r0)
{
  constexpr int G = FIN / 8;
  const int gl  = threadIdx.x & (G - 1);
  int gid = (int)((blockIdx.x * blockDim.x + threadIdx.x) / G);
  const int ng = (int)((gridDim.x * blockDim.x) / G);
  const int S = NN * RSUB;
  for(int s = gid; s < S; s += ng){
    int n = s / RSUB, rr = s - n * RSUB;
    int seg = n * RREL + r0 + rr;
    int beg = offs[seg], end = offs[seg + 1];
    float sc = inv[seg];
    float acc[8];
    #pragma unroll
    for(int i = 0; i < 8; i++) acc[i] = 0.f;
    int e = beg;
    for(; e + 2 <= end; e += 2){
      int s0 = spk[e] >> 3, s1 = spk[e + 1] >> 3;
      uint4 v0 = ((const uint4*)(hb + (size_t)s0 * FIN))[gl];
      uint4 v1 = ((const uint4*)(hb + (size_t)s1 * FIN))[gl];
      acc8(acc, v0);
      acc8(acc, v1);
    }
    if(e < end){
      uint4 v0 = ((const uint4*)(hb + (size_t)(spk[e] >> 3) * FIN))[gl];
      acc8(acc, v0);
    }
    uint4 o;
    o.x = (u32)f2b(acc[0] * sc) | ((u32)f2b(acc[1] * sc) << 16);
    o.y = (u32)f2b(acc[2] * sc) | ((u32)f2b(acc[3] * sc) << 16);
    o.z = (u32)f2b(acc[4] * sc) | ((u32)f2b(acc[5] * sc) << 16);
    o.w = (u32)f2b(acc[6] * sc) | ((u32)f2b(acc[7] * sc) << 16);
    ((uint4*)(agg + (size_t)n * LDW + rr * FIN))[gl] = o;
  }
}

// ---------------- unified GEMM: 128x128 out-tile, 8 waves, DEPTH-buf counted-vmcnt ----------------
// A[n][KA] + optional root block from Ax[n][128] (XROOT: ks>=32 wave-uniform).
// SWZ=1 (L1): xcd=bid&7, s=bid>>3, jc=s&1, bm=xcd+8*(s>>1) — jc pair same XCD.
// EPI=0: T store (bf16). EPI=1: bias+ELU -> dout(512)+hbout(256).

template<int K, int NJC, int EPI, int SWZ, int DEPTH, bool XROOT>
__global__ __launch_bounds__(512)
void dgemm_k(const u16* __restrict__ A, const u16* __restrict__ Bw,
             u16* __restrict__ T, const float* __restrict__ bias,
             float* __restrict__ dout, u16* __restrict__ hbout,
             const u16* __restrict__ Ax)
{
  constexpr int NKS = K / 32;
  constexpr int KA  = XROOT ? 1024 : K;    // A row stride
  constexpr int ASL = 512;
  constexpr int BSL = 512;
  __shared__ u16 lds[DEPTH][(ASL + BSL) * 8];
  int bm, jc;
  if constexpr(SWZ == 1){
    int d = (int)blockIdx.x;
    int x = d & 7, s = d >> 3;
    jc = s & 1;
    bm = x + 8 * (s >> 1);
    if(bm >= MT1) return;
  } else {
    bm = (int)blockIdx.x / NJC;
    jc = (int)blockIdx.x % NJC;
  }
  const int tid = threadIdx.x;
  const int wid = tid >> 6, lane = tid & 63;
  const int wm  = wid >> 1, wn = wid & 1;      // 4x2 waves, wave tile 32x64

  auto stage = [&](int ks, u16* l){
    u16* lA = l;
    u16* lB = l + ASL * 8;
    int koff = ks * 32;
    {
      int sb = wid * 64;
      int s  = sb + lane;
      int pair = s >> 3, cs = s & 7;
      int c    = cs ^ (pair & 7);
      int row  = pair * 2 + (c >> 2);
      int k8   = c & 3;
      int kk   = koff + k8 * 8;
      int rowg = bm * 128 + row; rowg = rowg < NN ? rowg : NN - 1;
      const u16* ga;
      if constexpr(XROOT){
        ga = (koff >= 1024) ? (Ax + (size_t)rowg * 128 + (kk - 1024))
                            : (A  + (size_t)rowg * KA  + kk);
      } else {
        ga = A + (size_t)rowg * KA + kk;
      }
      gload16(ga, lA + sb * 8);
    }
    {
      int sb = wid * 64;
      int s  = sb + lane;
      int pair = s >> 3, cs = s & 7;
      int c    = cs ^ (pair & 7);
      int row  = pair * 2 + (c >> 2);
      int k8   = c & 3;
      int kk   = koff + k8 * 8;
      gload16(Bw + ((size_t)(jc * 128 + row)) * K + kk, lB + sb * 8);
    }
  };

  auto ldfrag = [&](const u16* buf, int row, int k8){
    int pair = row >> 1;
    int c    = ((row & 1) << 2) + k8;
    int cs   = c ^ (pair & 7);
    return *(const short8*)(buf + pair * 64 + cs * 8);
  };

  f32x4 acc[2][4] = {};

  #pragma unroll
  for(int p = 0; p < DEPTH - 1; p++) stage(p, (u16*)lds[p]);
  for(int ks = 0; ks < NKS; ks++){
    // wait for buffer ks: outstanding = 2*min(DEPTH-1, NKS-ks); keep younger in flight
    if(ks <= NKS - DEPTH + 1){
      asm volatile("s_waitcnt vmcnt(%0)" :: "i"(2 * (DEPTH - 2)) : "memory");
    } else if(DEPTH == 4 && ks == NKS - 2){
      asm volatile("s_waitcnt vmcnt(2)" ::: "memory");
    } else {
      asm volatile("s_waitcnt vmcnt(0)" ::: "memory");
    }
    __builtin_amdgcn_sched_barrier(0);
    __builtin_amdgcn_s_barrier();
    __builtin_amdgcn_sched_barrier(0);
    if(ks + DEPTH - 1 < NKS) stage(ks + DEPTH - 1, (u16*)lds[(ks + DEPTH - 1) % DEPTH]);
    const u16* lA = (const u16*)lds[ks % DEPTH];
    const u16* lB = lA + ASL * 8;
    short8 af[2], bf4[4];
    #pragma unroll
    for(int m = 0; m < 2; m++) af[m] = ldfrag(lA, wm * 32 + m * 16 + (lane & 15), lane >> 4);
    #pragma unroll
    for(int n = 0; n < 4; n++) bf4[n] = ldfrag(lB, wn * 64 + n * 16 + (lane & 15), lane >> 4);
    #pragma unroll
    for(int m = 0; m < 2; m++)
      #pragma unroll
      for(int n = 0; n < 4; n++)
        acc[m][n] = __builtin_amdgcn_mfma_f32_16x16x32_bf16(af[m], bf4[n], acc[m][n], 0, 0, 0);
  }

  // epilogue; C/D layout: col = lane&15, row = (lane>>4)*4 + reg   [m89-verified]
  #pragma unroll
  for(int m = 0; m < 2; m++){
    #pragma unroll
    for(int j = 0; j < 4; j++){
      int grow = bm * 128 + wm * 32 + m * 16 + (lane >> 4) * 4 + j;
      if(grow >= NN) continue;
      #pragma unroll
      for(int n = 0; n < 4; n++){
        int lcol = wn * 64 + n * 16 + (lane & 15);
        if constexpr(EPI == 0){
          T[(size_t)grow * NTC + jc * 128 + lcol] = f2b(acc[m][n][j]);
        } else {
          int gcol = jc * 128 + lcol;
          float v = acc[m][n][j] + bias[gcol];
          v = v > 0.f ? v : expm1f(v);
          dout[(size_t)grow * 512 + gcol] = v;
          hbout[(size_t)grow * 256 + gcol] = f2b(v);
        }
      }
    }
  }
}

// ---------------- scatter-mean (L2/L3, output-side): flat 8-unrolled loop ----------------

template<bool HB>
__global__ __launch_bounds__(256)
void scat_k(const u16* __restrict__ T, const int* __restrict__ spk,
            const int* __restrict__ offs, const float* __restrict__ inv,
            const float* __restrict__ bias, float* __restrict__ dout, int dcol0,
            u16* __restrict__ hbout)
{
  const int gl = threadIdx.x & 15;
  int n = (int)((blockIdx.x * 256 + threadIdx.x) >> 4);
  if(n >= NN) return;
  const float* invn = inv + n * RREL;
  float acc[8];
  { // root group at col 1024 (unscaled)
    uint4 v = *(const uint4*)(T + (size_t)n * NTC + 1024 + gl * 8);
    acc[0] = bf2f(v.x & 0xffffu); acc[1] = bf2f(v.x >> 16);
    acc[2] = bf2f(v.y & 0xffffu); acc[3] = bf2f(v.y >> 16);
    acc[4] = bf2f(v.z & 0xffffu); acc[5] = bf2f(v.z >> 16);
    acc[6] = bf2f(v.w & 0xffffu); acc[7] = bf2f(v.w >> 16);
  }
  int e  = offs[n * RREL];
  int e1 = offs[n * RREL + RREL];
  for(; e + 8 <= e1; e += 8){
    int p[8];
    #pragma unroll
    for(int j = 0; j < 8; j++) p[j] = spk[e + j];
    uint4 v[8];
    #pragma unroll
    for(int j = 0; j < 8; j++)
      v[j] = *(const uint4*)(T + (size_t)(p[j] >> 3) * NTC + (p[j] & 7) * 128 + gl * 8);
    #pragma unroll
    for(int j = 0; j < 8; j++) fma8(acc, v[j], invn[p[j] & 7]);
  }
  for(; e + 4 <= e1; e += 4){
    int p0 = spk[e], p1 = spk[e + 1], p2 = spk[e + 2], p3 = spk[e + 3];
    uint4 v0 = *(const uint4*)(T + (size_t)(p0 >> 3) * NTC + (p0 & 7) * 128 + gl * 8);
    uint4 v1 = *(const uint4*)(T + (size_t)(p1 >> 3) * NTC + (p1 & 7) * 128 + gl * 8);
    uint4 v2 = *(const uint4*)(T + (size_t)(p2 >> 3) * NTC + (p2 & 7) * 128 + gl * 8);
    uint4 v3 = *(const uint4*)(T + (size_t)(p3 >> 3) * NTC + (p3 & 7) * 128 + gl * 8);
    fma8(acc, v0, invn[p0 & 7]); fma8(acc, v1, invn[p1 & 7]);
    fma8(acc, v2, invn[p2 & 7]); fma8(acc, v3, invn[p3 & 7]);
  }
  for(; e < e1; e++){
    int p0 = spk[e];
    uint4 v0 = *(const uint4*)(T + (size_t)(p0 >> 3) * NTC + (p0 & 7) * 128 + gl * 8);
    fma8(acc, v0, invn[p0 & 7]);
  }
  float o[8];
  #pragma unroll
  for(int i = 0; i < 8; i++){
    float v = acc[i] + bias[gl * 8 + i];
    o[i] = v > 0.f ? v : expm1f(v);
  }
  float4* dp = (float4*)(dout + (size_t)n * 512 + dcol0 + gl * 8);
  dp[0] = make_float4(o[0], o[1], o[2], o[3]);
  dp[1] = make_float4(o[4], o[5], o[6], o[7]);
  if(HB){
    uint4 hv;
    hv.x = (u32)f2b(o[0]) | ((u32)f2b(o[1]) << 16);
    hv.y = (u32)f2b(o[2]) | ((u32)f2b(o[3]) << 16);
    hv.z = (u32)f2b(o[4]) | ((u32)f2b(o[5]) << 16);
    hv.w = (u32)f2b(o[6]) | ((u32)f2b(o[7]) << 16);
    *(uint4*)(hbout + (size_t)n * 128 + gl * 8) = hv;
  }
}

// ---------------- host ----------------

extern "C" void kernel_launch(void* const* d_in, const int* in_sizes, int n_in,
                              void* d_out, int out_size, void* d_ws, size_t ws_size,
                              hipStream_t stream)
{
  const float* x     = (const float*)d_in[0];
  const int*   ei    = (const int*)d_in[1];   // [2, E] int32
  const int*   et    = (const int*)d_in[2];   // [E]
  const float* w1    = (const float*)d_in[3];
  const float* root1 = (const float*)d_in[4];
  const float* b1    = (const float*)d_in[5];
  const float* w2    = (const float*)d_in[6];
  const float* root2 = (const float*)d_in[7];
  const float* b2    = (const float*)d_in[8];
  const float* w3    = (const float*)d_in[9];
  const float* root3 = (const float*)d_in[10];
  const float* b3    = (const float*)d_in[11];
  float* out = (float*)d_out;

  const int* esrc = ei;
  const int* edst = ei + EE;

  char* w = (char*)d_ws;
  auto alloc = [&](size_t bytes)->char*{ char* p = w; w += (bytes + 255) & ~(size_t)255; return p; };
  int*   cnt   = (int*)  alloc((size_t)NRSEG * 4);
  int*   offs  = (int*)  alloc((size_t)(NRSEG + 1) * 4);
  int*   fill  = (int*)  alloc((size_t)NRSEG * 4);
  float* inv   = (float*)alloc((size_t)NRSEG * 4);
  int*   spk   = (int*)  alloc((size_t)EE * 4);
  u16*   xb    = (u16*)  alloc((size_t)NN * 128 * 2);
  u16*   h1b   = (u16*)  alloc((size_t)NN * 256 * 2);
  u16*   h2b   = (u16*)  alloc((size_t)NN * 128 * 2);
  u16*   wpL1  = (u16*)  alloc((size_t)256 * NTC * 2);   // [256][1152]
  u16*   wp2   = (u16*)  alloc((size_t)9 * 256 * 128 * 2);
  u16*   wp3   = (u16*)  alloc((size_t)9 * 128 * 128 * 2);
  int*   bsums = (int*)  alloc(1024 * 4);
  u16*   agg2  = (u16*)  alloc((size_t)NN * 1024 * 2);   // [N,1024]: 8 agg groups
  u16*   T     = (u16*)  alloc((size_t)NN * NTC * 2);    // L2/L3 dense transform
  (void)ws_size; (void)in_sizes; (void)n_in; (void)out_size;

  hipMemsetAsync(cnt,  0, (size_t)NRSEG * 4, stream);
  hipMemsetAsync(fill, 0, (size_t)NRSEG * 4, stream);

  count_k<<<(EE + 255) / 256, 256, 0, stream>>>(edst, et, cnt);
  scan1_k<<<NB, 256, 0, stream>>>(cnt, bsums);
  scan2_k<<<1, 256, 0, stream>>>(bsums);
  scan3i_k<<<NB, 256, 0, stream>>>(cnt, bsums, offs, inv);
  fill_k<<<(EE + 255) / 256, 256, 0, stream>>>(esrc, edst, et, offs, fill, spk);
  prep_pack_k<<<(PRT + 255) / 256, 256, 0, stream>>>(
      x, xb, w1, root1, wpL1, w2, root2, wp2, w3, root3, wp3);

  const int MT = (NN + 127) / 128;       // 391
  const int SB = (NN * 16 + 255) / 256;  // 3125 scatter blocks

  // Layer 1 (input-side agg, XCD-paired deep-pipelined dgemm)
  agg_k<128, 8, 1024><<<4096, 256, 0, stream>>>(xb, spk, offs, inv, agg2, 0);
  dgemm_k<NTC, 2, 1, 1, 4, true><<<784, 512, 0, stream>>>(
      agg2, wpL1, nullptr, b1, out, h1b, xb);

  // Layer 2 (output-side): T2 = h1 @ wp2^T [N,1152], then flat scatter-mean
  dgemm_k<256, 9, 0, 0, 3, false><<<MT * 9, 512, 0, stream>>>(
      h1b, wp2, T, nullptr, nullptr, nullptr, nullptr);
  scat_k<true><<<SB, 256, 0, stream>>>(T, spk, offs, inv, b2, out, 256, h2b);

  // Layer 3 (output-side): T3 = h2 @ wp3^T [N,1152], then flat scatter-mean
  dgemm_k<128, 9, 0, 0, 3, false><<<MT * 9, 512, 0, stream>>>(
      h2b, wp3, T, nullptr, nullptr, nullptr, nullptr);
  scat_k<false><<<SB, 256, 0, stream>>>(T, spk, offs, inv, b3, out, 384, nullptr);
}

// Round 16
// 402.480 us; speedup vs baseline: 1.0835x; 1.0212x over previous
//
#include <hip/hip_runtime.h>

// R-GCN (3 layers) on MI355X — Round 16 (consolidation).
// vs round 15: (1) fill[] array deleted — scan3i leaves cnt dead, so fill_k
// uses atomicSub(&cnt[seg],1) as the scatter cursor (one fewer memset
// dispatch, one fewer random stream); (2) L2/L3 dgemm get a bijective
// XCD-chunked swizzle (m204) so each A-panel's 9 jc-blocks land on ONE
// XCD's L2 instead of round-robining across all 8. Rest identical.

#define DEVI __device__ __forceinline__

constexpr int NN    = 50000;
constexpr int EE    = 800000;
constexpr int RREL  = 8;
constexpr int NRSEG = NN * RREL;          // 400000
constexpr int NTC   = 1152;               // 9 groups x 128
constexpr int MT1   = (NN + 127) / 128;   // 391 row panels

using u16 = unsigned short;
using u32 = unsigned int;
using u64 = unsigned long long;

typedef short short8 __attribute__((ext_vector_type(8)));
typedef float f32x4  __attribute__((ext_vector_type(4)));

DEVI float bf2f(u32 u){ union{u32 i; float f;} x; x.i = u << 16; return x.f; }
DEVI u16   f2b(float f){ u32 u = __float_as_uint(f); u32 r = u + 0x7fffu + ((u >> 16) & 1u); return (u16)(r >> 16); }

typedef const __attribute__((address_space(1))) u32 gas_u32;
typedef __attribute__((address_space(3))) u32       las_u32;
DEVI void gload16(const void* g, void* l){
  __builtin_amdgcn_global_load_lds((gas_u32*)(u64)g, (las_u32*)(u64)l, 16, 0, 0);
}

// ---------------- prep kernels ----------------

__global__ void count_k(const int* __restrict__ dst, const int* __restrict__ et, int* __restrict__ cnt){
  int e = blockIdx.x * 256 + threadIdx.x;
  if(e < EE) atomicAdd(&cnt[dst[e] * RREL + et[e]], 1);
}

constexpr int SCAN_E = 8;
constexpr int CHUNK  = 2048;
constexpr int NB     = (NRSEG + CHUNK - 1) / CHUNK;   // 196

__global__ void scan1_k(const int* __restrict__ cnt, int* __restrict__ bsums){
  __shared__ int sm[256];
  int b = blockIdx.x, t = threadIdx.x;
  int base = b * CHUNK + t * SCAN_E;
  int s = 0;
  #pragma unroll
  for(int j = 0; j < SCAN_E; j++){ int i = base + j; s += (i < NRSEG) ? cnt[i] : 0; }
  sm[t] = s; __syncthreads();
  for(int off = 128; off > 0; off >>= 1){ if(t < off) sm[t] += sm[t + off]; __syncthreads(); }
  if(t == 0) bsums[b] = sm[0];
}

__global__ void scan2_k(int* __restrict__ bsums){
  __shared__ int sm[256];
  int t = threadIdx.x;
  int v = (t < NB) ? bsums[t] : 0;
  sm[t] = v; __syncthreads();
  for(int off = 1; off < 256; off <<= 1){
    int x = (t >= off) ? sm[t - off] : 0; __syncthreads();
    sm[t] += x; __syncthreads();
  }
  if(t < NB) bsums[t] = sm[t] - v;   // exclusive
}

// scan3 + inv fused; after this kernel cnt is DEAD (reused as fill cursor)
__global__ void scan3i_k(const int* __restrict__ cnt, const int* __restrict__ bsums,
                         int* __restrict__ offs, float* __restrict__ inv){
  __shared__ int sm[256];
  int b = blockIdx.x, t = threadIdx.x;
  int base = b * CHUNK + t * SCAN_E;
  int loc[SCAN_E]; int cv[SCAN_E]; int run = 0;
  #pragma unroll
  for(int j = 0; j < SCAN_E; j++){
    int i = base + j; int c = (i < NRSEG) ? cnt[i] : 0;
    cv[j] = c; loc[j] = run; run += c;
  }
  sm[t] = run; __syncthreads();
  for(int off = 1; off < 256; off <<= 1){
    int x = (t >= off) ? sm[t - off] : 0; __syncthreads();
    sm[t] += x; __syncthreads();
  }
  int tb = bsums[b] + sm[t] - run;
  #pragma unroll
  for(int j = 0; j < SCAN_E; j++){
    int i = base + j;
    if(i < NRSEG){
      offs[i] = tb + loc[j];
      inv[i]  = 1.0f / (float)(cv[j] > 0 ? cv[j] : 1);
    }
  }
  if(b == 0 && t == 0) offs[NRSEG] = EE;
}

// spk[p] = (src << 3) | rel; cursor = atomicSub on (dead) cnt
__global__ void fill_k(const int* __restrict__ src, const int* __restrict__ dst, const int* __restrict__ et,
                       const int* __restrict__ offs, int* __restrict__ cnt, int* __restrict__ spk){
  int e = blockIdx.x * 256 + threadIdx.x;
  if(e < EE){
    int d = dst[e], r = et[e];
    int seg = d * RREL + r;
    int i = atomicSub(&cnt[seg], 1);          // i = old count .. 1
    spk[offs[seg] + i - 1] = (src[e] << 3) | r;
  }
}

// fused: castx (xb only) | wpL1 [256][1152] | wp2 | wp3
constexpr int PR0 = NN * 128;
constexpr int PR1 = 256 * NTC;
constexpr int PR2 = 9 * 256 * 128;
constexpr int PR3 = 9 * 128 * 128;
constexpr int PRT = PR0 + PR1 + PR2 + PR3;

__global__ void prep_pack_k(const float* __restrict__ x, u16* __restrict__ xb,
                            const float* __restrict__ w1, const float* __restrict__ root1, u16* __restrict__ wpL1,
                            const float* __restrict__ w2, const float* __restrict__ root2, u16* __restrict__ wp2,
                            const float* __restrict__ w3, const float* __restrict__ root3, u16* __restrict__ wp3){
  int idx = blockIdx.x * 256 + threadIdx.x;
  if(idx < PR0){
    xb[idx] = f2b(x[idx]);
    return;
  }
  idx -= PR0;
  if(idx < PR1){
    int o = idx / NTC, k = idx % NTC;
    int g = k >> 7, i = k & 127;
    float v = (g < RREL) ? w1[((size_t)g * 128 + i) * 256 + o] : root1[(size_t)i * 256 + o];
    wpL1[idx] = f2b(v);
    return;
  }
  idx -= PR1;
  if(idx < PR2){
    int i = idx % 256;
    int o = (idx / 256) % 128;
    int g = idx / (256 * 128);
    float v = (g < RREL) ? w2[((size_t)g * 256 + i) * 128 + o] : root2[(size_t)i * 128 + o];
    wp2[idx] = f2b(v);
    return;
  }
  idx -= PR2;
  if(idx < PR3){
    int i = idx % 128;
    int o = (idx / 128) % 128;
    int g = idx / (128 * 128);
    float v = (g < RREL) ? w3[((size_t)g * 128 + i) * 128 + o] : root3[(size_t)i * 128 + o];
    wp3[idx] = f2b(v);
  }
}

// ---------------- aggregation (L1, input-side): 16-lane group per segment ----------------

DEVI void acc8(float* a, uint4 v){
  a[0] += bf2f(v.x & 0xffffu); a[1] += bf2f(v.x >> 16);
  a[2] += bf2f(v.y & 0xffffu); a[3] += bf2f(v.y >> 16);
  a[4] += bf2f(v.z & 0xffffu); a[5] += bf2f(v.z >> 16);
  a[6] += bf2f(v.w & 0xffffu); a[7] += bf2f(v.w >> 16);
}

DEVI void fma8(float* a, uint4 v, float c){
  a[0] += c * bf2f(v.x & 0xffffu); a[1] += c * bf2f(v.x >> 16);
  a[2] += c * bf2f(v.y & 0xffffu); a[3] += c * bf2f(v.y >> 16);
  a[4] += c * bf2f(v.z & 0xffffu); a[5] += c * bf2f(v.z >> 16);
  a[6] += c * bf2f(v.w & 0xffffu); a[7] += c * bf2f(v.w >> 16);
}

template<int FIN, int RSUB, int LDW>
__global__ __launch_bounds__(256)
void agg_k(const u16* __restrict__ hb, const int* __restrict__ spk,
           const int* __restrict__ offs, const float* __restrict__ inv,
           u16* __restrict__ agg, int r0)
{
  constexpr int G = FIN / 8;
  const int gl  = threadIdx.x & (G - 1);
  int gid = (int)((blockIdx.x * blockDim.x + threadIdx.x) / G);
  const int ng = (int)((gridDim.x * blockDim.x) / G);
  const int S = NN * RSUB;
  for(int s = gid; s < S; s += ng){
    int n = s / RSUB, rr = s - n * RSUB;
    int seg = n * RREL + r0 + rr;
    int beg = offs[seg], end = offs[seg + 1];
    float sc = inv[seg];
    float acc[8];
    #pragma unroll
    for(int i = 0; i < 8; i++) acc[i] = 0.f;
    int e = beg;
    for(; e + 2 <= end; e += 2){
      int s0 = spk[e] >> 3, s1 = spk[e + 1] >> 3;
      uint4 v0 = ((const uint4*)(hb + (size_t)s0 * FIN))[gl];
      uint4 v1 = ((const uint4*)(hb + (size_t)s1 * FIN))[gl];
      acc8(acc, v0);
      acc8(acc, v1);
    }
    if(e < end){
      uint4 v0 = ((const uint4*)(hb + (size_t)(spk[e] >> 3) * FIN))[gl];
      acc8(acc, v0);
    }
    uint4 o;
    o.x = (u32)f2b(acc[0] * sc) | ((u32)f2b(acc[1] * sc) << 16);
    o.y = (u32)f2b(acc[2] * sc) | ((u32)f2b(acc[3] * sc) << 16);
    o.z = (u32)f2b(acc[4] * sc) | ((u32)f2b(acc[5] * sc) << 16);
    o.w = (u32)f2b(acc[6] * sc) | ((u32)f2b(acc[7] * sc) << 16);
    ((uint4*)(agg + (size_t)n * LDW + rr * FIN))[gl] = o;
  }
}

// ---------------- unified GEMM: 128x128 out-tile, 8 waves, DEPTH-buf counted-vmcnt ----------------
// SWZ=1 (L1): xcd=bid&7, s=bid>>3, jc=s&1, bm=xcd+8*(s>>1) — jc pair same XCD.
// SWZ=2 (L2/L3): bijective XCD-chunk (m204) — all 9 jc of a panel same XCD.
// EPI=0: T store (bf16). EPI=1: bias+ELU -> dout(512)+hbout(256).

template<int K, int NJC, int EPI, int SWZ, int DEPTH, bool XROOT>
__global__ __launch_bounds__(512)
void dgemm_k(const u16* __restrict__ A, const u16* __restrict__ Bw,
             u16* __restrict__ T, const float* __restrict__ bias,
             float* __restrict__ dout, u16* __restrict__ hbout,
             const u16* __restrict__ Ax)
{
  constexpr int NKS = K / 32;
  constexpr int KA  = XROOT ? 1024 : K;    // A row stride
  constexpr int ASL = 512;
  constexpr int BSL = 512;
  __shared__ u16 lds[DEPTH][(ASL + BSL) * 8];
  int bm, jc;
  if constexpr(SWZ == 1){
    int d = (int)blockIdx.x;
    int x = d & 7, s = d >> 3;
    jc = s & 1;
    bm = x + 8 * (s >> 1);
    if(bm >= MT1) return;
  } else if constexpr(SWZ == 2){
    constexpr int NWG = MT1 * NJC;
    constexpr int Q = NWG / 8, R = NWG % 8;
    int d = (int)blockIdx.x;
    int xcd = d & 7, j = d >> 3;
    int wg = (xcd < R ? xcd * (Q + 1) : R * (Q + 1) + (xcd - R) * Q) + j;
    bm = wg / NJC;
    jc = wg % NJC;
  } else {
    bm = (int)blockIdx.x / NJC;
    jc = (int)blockIdx.x % NJC;
  }
  const int tid = threadIdx.x;
  const int wid = tid >> 6, lane = tid & 63;
  const int wm  = wid >> 1, wn = wid & 1;      // 4x2 waves, wave tile 32x64

  auto stage = [&](int ks, u16* l){
    u16* lA = l;
    u16* lB = l + ASL * 8;
    int koff = ks * 32;
    {
      int sb = wid * 64;
      int s  = sb + lane;
      int pair = s >> 3, cs = s & 7;
      int c    = cs ^ (pair & 7);
      int row  = pair * 2 + (c >> 2);
      int k8   = c & 3;
      int kk   = koff + k8 * 8;
      int rowg = bm * 128 + row; rowg = rowg < NN ? rowg : NN - 1;
      const u16* ga;
      if constexpr(XROOT){
        ga = (koff >= 1024) ? (Ax + (size_t)rowg * 128 + (kk - 1024))
                            : (A  + (size_t)rowg * KA  + kk);
      } else {
        ga = A + (size_t)rowg * KA + kk;
      }
      gload16(ga, lA + sb * 8);
    }
    {
      int sb = wid * 64;
      int s  = sb + lane;
      int pair = s >> 3, cs = s & 7;
      int c    = cs ^ (pair & 7);
      int row  = pair * 2 + (c >> 2);
      int k8   = c & 3;
      int kk   = koff + k8 * 8;
      gload16(Bw + ((size_t)(jc * 128 + row)) * K + kk, lB + sb * 8);
    }
  };

  auto ldfrag = [&](const u16* buf, int row, int k8){
    int pair = row >> 1;
    int c    = ((row & 1) << 2) + k8;
    int cs   = c ^ (pair & 7);
    return *(const short8*)(buf + pair * 64 + cs * 8);
  };

  f32x4 acc[2][4] = {};

  #pragma unroll
  for(int p = 0; p < DEPTH - 1; p++) stage(p, (u16*)lds[p]);
  for(int ks = 0; ks < NKS; ks++){
    if(ks <= NKS - DEPTH + 1){
      asm volatile("s_waitcnt vmcnt(%0)" :: "i"(2 * (DEPTH - 2)) : "memory");
    } else if(DEPTH == 4 && ks == NKS - 2){
      asm volatile("s_waitcnt vmcnt(2)" ::: "memory");
    } else {
      asm volatile("s_waitcnt vmcnt(0)" ::: "memory");
    }
    __builtin_amdgcn_sched_barrier(0);
    __builtin_amdgcn_s_barrier();
    __builtin_amdgcn_sched_barrier(0);
    if(ks + DEPTH - 1 < NKS) stage(ks + DEPTH - 1, (u16*)lds[(ks + DEPTH - 1) % DEPTH]);
    const u16* lA = (const u16*)lds[ks % DEPTH];
    const u16* lB = lA + ASL * 8;
    short8 af[2], bf4[4];
    #pragma unroll
    for(int m = 0; m < 2; m++) af[m] = ldfrag(lA, wm * 32 + m * 16 + (lane & 15), lane >> 4);
    #pragma unroll
    for(int n = 0; n < 4; n++) bf4[n] = ldfrag(lB, wn * 64 + n * 16 + (lane & 15), lane >> 4);
    #pragma unroll
    for(int m = 0; m < 2; m++)
      #pragma unroll
      for(int n = 0; n < 4; n++)
        acc[m][n] = __builtin_amdgcn_mfma_f32_16x16x32_bf16(af[m], bf4[n], acc[m][n], 0, 0, 0);
  }

  // epilogue; C/D layout: col = lane&15, row = (lane>>4)*4 + reg   [m89-verified]
  #pragma unroll
  for(int m = 0; m < 2; m++){
    #pragma unroll
    for(int j = 0; j < 4; j++){
      int grow = bm * 128 + wm * 32 + m * 16 + (lane >> 4) * 4 + j;
      if(grow >= NN) continue;
      #pragma unroll
      for(int n = 0; n < 4; n++){
        int lcol = wn * 64 + n * 16 + (lane & 15);
        if constexpr(EPI == 0){
          T[(size_t)grow * NTC + jc * 128 + lcol] = f2b(acc[m][n][j]);
        } else {
          int gcol = jc * 128 + lcol;
          float v = acc[m][n][j] + bias[gcol];
          v = v > 0.f ? v : expm1f(v);
          dout[(size_t)grow * 512 + gcol] = v;
          hbout[(size_t)grow * 256 + gcol] = f2b(v);
        }
      }
    }
  }
}

// ---------------- scatter-mean (L2/L3, output-side): flat 8-unrolled loop ----------------

template<bool HB>
__global__ __launch_bounds__(256)
void scat_k(const u16* __restrict__ T, const int* __restrict__ spk,
            const int* __restrict__ offs, const float* __restrict__ inv,
            const float* __restrict__ bias, float* __restrict__ dout, int dcol0,
            u16* __restrict__ hbout)
{
  const int gl = threadIdx.x & 15;
  int n = (int)((blockIdx.x * 256 + threadIdx.x) >> 4);
  if(n >= NN) return;
  const float* invn = inv + n * RREL;
  float acc[8];
  { // root group at col 1024 (unscaled)
    uint4 v = *(const uint4*)(T + (size_t)n * NTC + 1024 + gl * 8);
    acc[0] = bf2f(v.x & 0xffffu); acc[1] = bf2f(v.x >> 16);
    acc[2] = bf2f(v.y & 0xffffu); acc[3] = bf2f(v.y >> 16);
    acc[4] = bf2f(v.z & 0xffffu); acc[5] = bf2f(v.z >> 16);
    acc[6] = bf2f(v.w & 0xffffu); acc[7] = bf2f(v.w >> 16);
  }
  int e  = offs[n * RREL];
  int e1 = offs[n * RREL + RREL];
  for(; e + 8 <= e1; e += 8){
    int p[8];
    #pragma unroll
    for(int j = 0; j < 8; j++) p[j] = spk[e + j];
    uint4 v[8];
    #pragma unroll
    for(int j = 0; j < 8; j++)
      v[j] = *(const uint4*)(T + (size_t)(p[j] >> 3) * NTC + (p[j] & 7) * 128 + gl * 8);
    #pragma unroll
    for(int j = 0; j < 8; j++) fma8(acc, v[j], invn[p[j] & 7]);
  }
  for(; e + 4 <= e1; e += 4){
    int p0 = spk[e], p1 = spk[e + 1], p2 = spk[e + 2], p3 = spk[e + 3];
    uint4 v0 = *(const uint4*)(T + (size_t)(p0 >> 3) * NTC + (p0 & 7) * 128 + gl * 8);
    uint4 v1 = *(const uint4*)(T + (size_t)(p1 >> 3) * NTC + (p1 & 7) * 128 + gl * 8);
    uint4 v2 = *(const uint4*)(T + (size_t)(p2 >> 3) * NTC + (p2 & 7) * 128 + gl * 8);
    uint4 v3 = *(const uint4*)(T + (size_t)(p3 >> 3) * NTC + (p3 & 7) * 128 + gl * 8);
    fma8(acc, v0, invn[p0 & 7]); fma8(acc, v1, invn[p1 & 7]);
    fma8(acc, v2, invn[p2 & 7]); fma8(acc, v3, invn[p3 & 7]);
  }
  for(; e < e1; e++){
    int p0 = spk[e];
    uint4 v0 = *(const uint4*)(T + (size_t)(p0 >> 3) * NTC + (p0 & 7) * 128 + gl * 8);
    fma8(acc, v0, invn[p0 & 7]);
  }
  float o[8];
  #pragma unroll
  for(int i = 0; i < 8; i++){
    float v = acc[i] + bias[gl * 8 + i];
    o[i] = v > 0.f ? v : expm1f(v);
  }
  float4* dp = (float4*)(dout + (size_t)n * 512 + dcol0 + gl * 8);
  dp[0] = make_float4(o[0], o[1], o[2], o[3]);
  dp[1] = make_float4(o[4], o[5], o[6], o[7]);
  if(HB){
    uint4 hv;
    hv.x = (u32)f2b(o[0]) | ((u32)f2b(o[1]) << 16);
    hv.y = (u32)f2b(o[2]) | ((u32)f2b(o[3]) << 16);
    hv.z = (u32)f2b(o[4]) | ((u32)f2b(o[5]) << 16);
    hv.w = (u32)f2b(o[6]) | ((u32)f2b(o[7]) << 16);
    *(uint4*)(hbout + (size_t)n * 128 + gl * 8) = hv;
  }
}

// ---------------- host ----------------

extern "C" void kernel_launch(void* const* d_in, const int* in_sizes, int n_in,
                              void* d_out, int out_size, void* d_ws, size_t ws_size,
                              hipStream_t stream)
{
  const float* x     = (const float*)d_in[0];
  const int*   ei    = (const int*)d_in[1];   // [2, E] int32
  const int*   et    = (const int*)d_in[2];   // [E]
  const float* w1    = (const float*)d_in[3];
  const float* root1 = (const float*)d_in[4];
  const float* b1    = (const float*)d_in[5];
  const float* w2    = (const float*)d_in[6];
  const float* root2 = (const float*)d_in[7];
  const float* b2    = (const float*)d_in[8];
  const float* w3    = (const float*)d_in[9];
  const float* root3 = (const float*)d_in[10];
  const float* b3    = (const float*)d_in[11];
  float* out = (float*)d_out;

  const int* esrc = ei;
  const int* edst = ei + EE;

  char* w = (char*)d_ws;
  auto alloc = [&](size_t bytes)->char*{ char* p = w; w += (bytes + 255) & ~(size_t)255; return p; };
  int*   cnt   = (int*)  alloc((size_t)NRSEG * 4);
  int*   offs  = (int*)  alloc((size_t)(NRSEG + 1) * 4);
  float* inv   = (float*)alloc((size_t)NRSEG * 4);
  int*   spk   = (int*)  alloc((size_t)EE * 4);
  u16*   xb    = (u16*)  alloc((size_t)NN * 128 * 2);
  u16*   h1b   = (u16*)  alloc((size_t)NN * 256 * 2);
  u16*   h2b   = (u16*)  alloc((size_t)NN * 128 * 2);
  u16*   wpL1  = (u16*)  alloc((size_t)256 * NTC * 2);   // [256][1152]
  u16*   wp2   = (u16*)  alloc((size_t)9 * 256 * 128 * 2);
  u16*   wp3   = (u16*)  alloc((size_t)9 * 128 * 128 * 2);
  int*   bsums = (int*)  alloc(1024 * 4);
  u16*   agg2  = (u16*)  alloc((size_t)NN * 1024 * 2);   // [N,1024]: 8 agg groups
  u16*   T     = (u16*)  alloc((size_t)NN * NTC * 2);    // L2/L3 dense transform
  (void)ws_size; (void)in_sizes; (void)n_in; (void)out_size;

  hipMemsetAsync(cnt, 0, (size_t)NRSEG * 4, stream);

  count_k<<<(EE + 255) / 256, 256, 0, stream>>>(edst, et, cnt);
  scan1_k<<<NB, 256, 0, stream>>>(cnt, bsums);
  scan2_k<<<1, 256, 0, stream>>>(bsums);
  scan3i_k<<<NB, 256, 0, stream>>>(cnt, bsums, offs, inv);
  fill_k<<<(EE + 255) / 256, 256, 0, stream>>>(esrc, edst, et, offs, cnt, spk);
  prep_pack_k<<<(PRT + 255) / 256, 256, 0, stream>>>(
      x, xb, w1, root1, wpL1, w2, root2, wp2, w3, root3, wp3);

  const int MT = (NN + 127) / 128;       // 391
  const int SB = (NN * 16 + 255) / 256;  // 3125 scatter blocks

  // Layer 1 (input-side agg, XCD-paired deep-pipelined dgemm)
  agg_k<128, 8, 1024><<<4096, 256, 0, stream>>>(xb, spk, offs, inv, agg2, 0);
  dgemm_k<NTC, 2, 1, 1, 4, true><<<784, 512, 0, stream>>>(
      agg2, wpL1, nullptr, b1, out, h1b, xb);

  // Layer 2 (output-side): T2 = h1 @ wp2^T [N,1152], then flat scatter-mean
  dgemm_k<256, 9, 0, 2, 3, false><<<MT * 9, 512, 0, stream>>>(
      h1b, wp2, T, nullptr, nullptr, nullptr, nullptr);
  scat_k<true><<<SB, 256, 0, stream>>>(T, spk, offs, inv, b2, out, 256, h2b);

  // Layer 3 (output-side): T3 = h2 @ wp3^T [N,1152], then flat scatter-mean
  dgemm_k<128, 9, 0, 2, 3, false><<<MT * 9, 512, 0, stream>>>(
      h2b, wp3, T, nullptr, nullptr, nullptr, nullptr);
  scat_k<false><<<SB, 256, 0, stream>>>(T, spk, offs, inv, b3, out, 384, nullptr);
}